// Round 4
// baseline (915.108 us; speedup 1.0000x reference)
//
#include <hip/hip_runtime.h>
#include <hip/hip_bf16.h>

#define TN 49      // tokens per window
#define TC 192     // channels
#define NH 6       // heads
#define NP 64      // padded tokens
#define NN (TN*TN) // 2401
#define SSTR 200   // SC row stride (bf16 elems) -> 400B
#define KSTR 40    // KSh row stride (tokens x 32 d) -> 80B
#define VSTR 72    // VTh row stride (32 d x tokens) -> 144B

typedef __bf16 bf16x8 __attribute__((ext_vector_type(8)));
typedef float  f32x4  __attribute__((ext_vector_type(4)));

static constexpr float SCALE = 0.17677669529663687f;  // 32^-0.5

__device__ __forceinline__ unsigned short f2bf(float f) {
    union { float f; unsigned u; } v; v.f = f;
    unsigned r = v.u + 0x7FFFu + ((v.u >> 16) & 1u);   // RNE
    return (unsigned short)(r >> 16);
}

// ---------------------------------------------------------------------------
// Kernel 0: prep — weight fp32->bf16 AND cmb[wi][h][n][m] = bias + mask
// ---------------------------------------------------------------------------
__global__ __launch_bounds__(256) void prep_kernel(
    const float* __restrict__ qw, const float* __restrict__ pw,
    const float* __restrict__ bt, const int* __restrict__ ridx,
    const float* __restrict__ mask,
    unsigned short* __restrict__ qwb, unsigned short* __restrict__ pwb,
    float* __restrict__ cmb, int total)
{
    int idx = blockIdx.x * 256 + threadIdx.x;
    const int NQW = 576 * 192;
    const int NPW = 192 * 192;
    if (idx < NQW) { qwb[idx] = f2bf(qw[idx]); return; }
    idx -= NQW;
    if (idx < NPW) { pwb[idx] = f2bf(pw[idx]); return; }
    idx -= NPW;
    if (idx < total) {
        int nm = idx % NN;
        int hw = idx / NN;
        int h  = hw % NH;
        int wi = hw / NH;
        cmb[idx] = bt[ridx[nm] * NH + h] + mask[(size_t)wi * NN + nm];
    }
}

// ---------------------------------------------------------------------------
// Kernel 1: fused qkv + attention + proj. One block per window, 4 waves.
// LDS = 34.6 KB -> 4 blocks/CU (16 waves/CU). waves_per_eu pinned to (4,4)
// so the allocator uses the full 128-VGPR budget for this tier instead of
// squeezing to 64 and spilling (round-3 regression: +350 MB scratch traffic).
// ---------------------------------------------------------------------------
__global__ __launch_bounds__(256)
__attribute__((amdgpu_waves_per_eu(4, 4)))
void fused_kernel(
    const float* __restrict__ x, const float* __restrict__ cmb,
    const unsigned short* __restrict__ wqkv, const float* __restrict__ qb,
    const unsigned short* __restrict__ wp, const float* __restrict__ pb,
    float* __restrict__ out, int nW)
{
    __shared__ __align__(16) unsigned short SC[NP * SSTR];    // 25600 B
    __shared__ __align__(16) unsigned short KSh[NP * KSTR];   //  5120 B
    __shared__ __align__(16) unsigned short VTh[32 * VSTR];   //  4608 B
    // total 35328 B -> 4 blocks/CU

    const int b    = blockIdx.x;
    const int t    = threadIdx.x;
    const int w    = t >> 6;
    const int lane = t & 63;
    const int l15  = lane & 15;
    const int quad = lane >> 4;
    const int row0 = w * 16 + quad * 4;   // C-fragment token-row base
    const int arow = w * 16 + l15;        // A-fragment token row
    const float NEG_INF = -__builtin_inff();

    // ---- x A-fragments: direct global -> registers (zero rows >= TN) ----
    bf16x8 af[6];
    {
        const float* xr = x + (size_t)b * TN * TC + (size_t)arow * TC + quad * 8;
        const bool rv = (arow < TN);
#pragma unroll
        for (int kt = 0; kt < 6; ++kt) {
            float4 a0 = {0.f, 0.f, 0.f, 0.f}, a1 = {0.f, 0.f, 0.f, 0.f};
            if (rv) {
                a0 = *(const float4*)(xr + kt * 32);
                a1 = *(const float4*)(xr + kt * 32 + 4);
            }
            union { bf16x8 v; unsigned short s[8]; } u;
            u.s[0] = f2bf(a0.x); u.s[1] = f2bf(a0.y);
            u.s[2] = f2bf(a0.z); u.s[3] = f2bf(a0.w);
            u.s[4] = f2bf(a1.x); u.s[5] = f2bf(a1.y);
            u.s[6] = f2bf(a1.z); u.s[7] = f2bf(a1.w);
            af[kt] = u.v;
        }
    }

    // ---- Q = (x Wq^T + b) * scale -> SC (wave-private rows, no barrier) ----
#pragma unroll 4
    for (int ct = 0; ct < 12; ++ct) {
        f32x4 acc = {0.f, 0.f, 0.f, 0.f};
        const unsigned short* wr = wqkv + (size_t)(ct * 16 + l15) * TC + quad * 8;
#pragma unroll
        for (int kt = 0; kt < 6; ++kt)
            acc = __builtin_amdgcn_mfma_f32_16x16x32_bf16(
                af[kt], *(const bf16x8*)(wr + kt * 32), acc, 0, 0, 0);
        const int d = ct * 16 + l15;
        const float bias = qb[d];
#pragma unroll
        for (int r = 0; r < 4; ++r)
            SC[(row0 + r) * SSTR + d] = f2bf((acc[r] + bias) * SCALE);
    }
    // Q fragments for all heads into registers (own rows -> no barrier)
    bf16x8 aq[NH];
#pragma unroll
    for (int h = 0; h < NH; ++h)
        aq[h] = *(const bf16x8*)&SC[arow * SSTR + h * 32 + quad * 8];

    const float* cmbb = cmb + (size_t)((b % nW) * NH) * NN;
    f32x4 oacc0[2], oacc1[2];

#pragma unroll 1
    for (int h = 0; h < NH; ++h) {
        if (h) __syncthreads();   // all waves done reading prev KSh/VTh

        // prefetch cmb tile into regs (hides L2 latency under K/V MFMAs)
        const float* cp = cmbb + (size_t)h * NN;
        float cpv[4][4];
#pragma unroll
        for (int tc = 0; tc < 4; ++tc) {
            int m = tc * 16 + l15;
#pragma unroll
            for (int r = 0; r < 4; ++r) {
                int n = row0 + r;
                cpv[tc][r] = (m < TN && n < TN) ? cp[n * TN + m] : 0.f;
            }
        }

        // ---- K_h, V_h: 4 independent MFMA chains, B streamed from L2 ----
#pragma unroll
        for (int cc = 0; cc < 4; ++cc) {
            const int mat = cc >> 1;           // 0 = K, 1 = V
            const int ct  = cc & 1;
            const unsigned short* wr =
                wqkv + (size_t)((1 + mat) * TC + h * 32 + ct * 16 + l15) * TC + quad * 8;
            f32x4 acc = {0.f, 0.f, 0.f, 0.f};
#pragma unroll
            for (int kt = 0; kt < 6; ++kt)
                acc = __builtin_amdgcn_mfma_f32_16x16x32_bf16(
                    af[kt], *(const bf16x8*)(wr + kt * 32), acc, 0, 0, 0);
            const int d = ct * 16 + l15;       // 0..31 within head
            const float bias = qb[(1 + mat) * TC + h * 32 + d];
            if (mat == 0) {
#pragma unroll
                for (int r = 0; r < 4; ++r)
                    KSh[(row0 + r) * KSTR + d] = f2bf(acc[r] + bias);
            } else {
#pragma unroll
                for (int r = 0; r < 4; ++r)
                    VTh[d * VSTR + row0 + r] = f2bf(acc[r] + bias);
            }
        }
        __syncthreads();          // KSh/VTh visible to all waves

        // ---- S = Q K^T : 4 col-tiles, K=32 ----
        f32x4 sacc[4];
#pragma unroll
        for (int tc = 0; tc < 4; ++tc) {
            bf16x8 bk = *(const bf16x8*)&KSh[(tc * 16 + l15) * KSTR + quad * 8];
            f32x4 z = {0.f, 0.f, 0.f, 0.f};
            sacc[tc] = __builtin_amdgcn_mfma_f32_16x16x32_bf16(aq[h], bk, z, 0, 0, 0);
        }
        // ---- softmax (bias+mask already in cpv regs) ----
        float sv[4][4];
        float mx[4] = {NEG_INF, NEG_INF, NEG_INF, NEG_INF};
#pragma unroll
        for (int tc = 0; tc < 4; ++tc) {
            int m = tc * 16 + l15;
#pragma unroll
            for (int r = 0; r < 4; ++r) {
                float s = (m < TN) ? sacc[tc][r] + cpv[tc][r] : NEG_INF;
                sv[tc][r] = s;
                mx[r] = fmaxf(mx[r], s);
            }
        }
#pragma unroll
        for (int r = 0; r < 4; ++r) {
            mx[r] = fmaxf(mx[r], __shfl_xor(mx[r], 1));
            mx[r] = fmaxf(mx[r], __shfl_xor(mx[r], 2));
            mx[r] = fmaxf(mx[r], __shfl_xor(mx[r], 4));
            mx[r] = fmaxf(mx[r], __shfl_xor(mx[r], 8));
        }
        float sm[4] = {0.f, 0.f, 0.f, 0.f};
#pragma unroll
        for (int tc = 0; tc < 4; ++tc)
#pragma unroll
            for (int r = 0; r < 4; ++r) {
                float p = __expf(sv[tc][r] - mx[r]);
                sv[tc][r] = p;
                sm[r] += p;
            }
#pragma unroll
        for (int r = 0; r < 4; ++r) {
            sm[r] += __shfl_xor(sm[r], 1);
            sm[r] += __shfl_xor(sm[r], 2);
            sm[r] += __shfl_xor(sm[r], 4);
            sm[r] += __shfl_xor(sm[r], 8);
            sm[r] = 1.0f / sm[r];
        }
        // P -> SC cols 0..63 (wave-private rows)
#pragma unroll
        for (int tc = 0; tc < 4; ++tc)
#pragma unroll
            for (int r = 0; r < 4; ++r)
                SC[(row0 + r) * SSTR + tc * 16 + l15] = f2bf(sv[tc][r] * sm[r]);

        // ---- out_h = P V : 2 d-tiles, K=64 ----
#pragma unroll
        for (int dt = 0; dt < 2; ++dt) {
            f32x4 pacc = {0.f, 0.f, 0.f, 0.f};
#pragma unroll
            for (int kt = 0; kt < 2; ++kt) {
                bf16x8 ap = *(const bf16x8*)&SC[arow * SSTR + kt * 32 + quad * 8];
                bf16x8 bv = *(const bf16x8*)&VTh[(dt * 16 + l15) * VSTR + kt * 32 + quad * 8];
                pacc = __builtin_amdgcn_mfma_f32_16x16x32_bf16(ap, bv, pacc, 0, 0, 0);
            }
            if (h == 0)      oacc0[dt] = pacc;
            else if (h == 1) oacc1[dt] = pacc;
            else {
                // Ao_h -> SC cols h*32.. (own rows; no clash with P cols 0..63)
#pragma unroll
                for (int r = 0; r < 4; ++r)
                    SC[(row0 + r) * SSTR + h * 32 + dt * 16 + l15] = f2bf(pacc[r]);
            }
        }
    }

    // ---- Ao heads 0,1 -> SC cols 0..63 (P region dead) ----
#pragma unroll
    for (int dt = 0; dt < 2; ++dt)
#pragma unroll
        for (int r = 0; r < 4; ++r) {
            SC[(row0 + r) * SSTR + dt * 16 + l15]      = f2bf(oacc0[dt][r]);
            SC[(row0 + r) * SSTR + 32 + dt * 16 + l15] = f2bf(oacc1[dt][r]);
        }

    bf16x8 pf[6];
#pragma unroll
    for (int kt = 0; kt < 6; ++kt)
        pf[kt] = *(const bf16x8*)&SC[arow * SSTR + kt * 32 + quad * 8];

    // ---- proj: out = Ao Wp^T + b, Wp streamed from L2 ----
#pragma unroll 4
    for (int ct = 0; ct < 12; ++ct) {
        f32x4 acc = {0.f, 0.f, 0.f, 0.f};
        const unsigned short* wr = wp + (size_t)(ct * 16 + l15) * TC + quad * 8;
#pragma unroll
        for (int kt = 0; kt < 6; ++kt)
            acc = __builtin_amdgcn_mfma_f32_16x16x32_bf16(
                pf[kt], *(const bf16x8*)(wr + kt * 32), acc, 0, 0, 0);
        const int c = ct * 16 + l15;
        const float bias = pb[c];
#pragma unroll
        for (int r = 0; r < 4; ++r) {
            int n = row0 + r;
            if (n < TN)
                out[((size_t)b * TN + n) * TC + c] = acc[r] + bias;
        }
    }
}

extern "C" void kernel_launch(void* const* d_in, const int* in_sizes, int n_in,
                              void* d_out, int out_size, void* d_ws, size_t ws_size,
                              hipStream_t stream) {
    const float* x    = (const float*)d_in[0];
    const float* mask = (const float*)d_in[1];
    const float* bt   = (const float*)d_in[2];
    const float* qw   = (const float*)d_in[3];
    const float* qb   = (const float*)d_in[4];
    const float* pw   = (const float*)d_in[5];
    const float* pb   = (const float*)d_in[6];
    const int*   ridx = (const int*)d_in[7];

    const int B  = in_sizes[0] / (TN * TC);   // 4096 windows
    const int nW = in_sizes[1] / (TN * TN);   // 64

    unsigned short* wqkvb = (unsigned short*)d_ws;            // 576*192 bf16
    unsigned short* wpb   = wqkvb + 576 * 192;                // 192*192 bf16
    float*          cmb   = (float*)(wpb + 192 * 192);        // nW*6*2401 f32 (~3.7 MB)

    const int total = nW * NH * NN;
    const int prep_threads = 576 * 192 + 192 * 192 + total;

    hipLaunchKernelGGL(prep_kernel, dim3((prep_threads + 255) / 256), dim3(256), 0, stream,
                       qw, pw, bt, ridx, mask, wqkvb, wpb, cmb, total);
    hipLaunchKernelGGL(fused_kernel, dim3(B), dim3(256), 0, stream,
                       x, cmb, wqkvb, qb, wpb, pb, (float*)d_out, nW);
}

// Round 5
// 845.706 us; speedup vs baseline: 1.0821x; 1.0821x over previous
//
#include <hip/hip_runtime.h>
#include <hip/hip_bf16.h>

#define TN 49      // tokens per window
#define TC 192     // channels
#define NH 6       // heads
#define NP 64      // padded tokens
#define NN (TN*TN) // 2401
#define SSTR 200   // SC row stride (bf16 elems) -> 400B
#define KSTR 40    // KSh row stride (tokens x 32 d) -> 80B
#define VSTR 72    // VTh row stride (32 d x tokens) -> 144B

typedef __bf16 bf16x8 __attribute__((ext_vector_type(8)));
typedef float  f32x4  __attribute__((ext_vector_type(4)));

static constexpr float SCALE = 0.17677669529663687f;  // 32^-0.5

__device__ __forceinline__ unsigned short f2bf(float f) {
    union { float f; unsigned u; } v; v.f = f;
    unsigned r = v.u + 0x7FFFu + ((v.u >> 16) & 1u);   // RNE
    return (unsigned short)(r >> 16);
}

// ---------------------------------------------------------------------------
// Kernel 0: prep — weight fp32->bf16 AND cmb[wi][h][n][m] = bias + mask
// ---------------------------------------------------------------------------
__global__ __launch_bounds__(256) void prep_kernel(
    const float* __restrict__ qw, const float* __restrict__ pw,
    const float* __restrict__ bt, const int* __restrict__ ridx,
    const float* __restrict__ mask,
    unsigned short* __restrict__ qwb, unsigned short* __restrict__ pwb,
    float* __restrict__ cmb, int total)
{
    int idx = blockIdx.x * 256 + threadIdx.x;
    const int NQW = 576 * 192;
    const int NPW = 192 * 192;
    if (idx < NQW) { qwb[idx] = f2bf(qw[idx]); return; }
    idx -= NQW;
    if (idx < NPW) { pwb[idx] = f2bf(pw[idx]); return; }
    idx -= NPW;
    if (idx < total) {
        int nm = idx % NN;
        int hw = idx / NN;
        int h  = hw % NH;
        int wi = hw / NH;
        cmb[idx] = bt[ridx[nm] * NH + h] + mask[(size_t)wi * NN + nm];
    }
}

// ---------------------------------------------------------------------------
// Kernel 1: fused qkv + attention + proj. One block per window, 4 waves.
// LDS = 34.6 KB -> 4 blocks/CU (16 waves/CU). Head loop FULLY UNROLLED so
// every local array index is compile-time (rule #20: runtime-indexed
// ext_vector arrays go to scratch — that was round-3/4's +300 MB regression).
// ---------------------------------------------------------------------------
__global__ __launch_bounds__(256)
__attribute__((amdgpu_waves_per_eu(4, 4)))
void fused_kernel(
    const float* __restrict__ x, const float* __restrict__ cmb,
    const unsigned short* __restrict__ wqkv, const float* __restrict__ qb,
    const unsigned short* __restrict__ wp, const float* __restrict__ pb,
    float* __restrict__ out, int nW)
{
    __shared__ __align__(16) unsigned short SC[NP * SSTR];    // 25600 B
    __shared__ __align__(16) unsigned short KSh[NP * KSTR];   //  5120 B
    __shared__ __align__(16) unsigned short VTh[32 * VSTR];   //  4608 B
    // total 35328 B -> 4 blocks/CU

    const int b    = blockIdx.x;
    const int t    = threadIdx.x;
    const int w    = t >> 6;
    const int lane = t & 63;
    const int l15  = lane & 15;
    const int quad = lane >> 4;
    const int row0 = w * 16 + quad * 4;   // C-fragment token-row base
    const int arow = w * 16 + l15;        // A-fragment token row
    const float NEG_INF = -__builtin_inff();

    // ---- x A-fragments: direct global -> registers (zero rows >= TN) ----
    bf16x8 af[6];
    {
        const float* xr = x + (size_t)b * TN * TC + (size_t)arow * TC + quad * 8;
        const bool rv = (arow < TN);
#pragma unroll
        for (int kt = 0; kt < 6; ++kt) {
            float4 a0 = {0.f, 0.f, 0.f, 0.f}, a1 = {0.f, 0.f, 0.f, 0.f};
            if (rv) {
                a0 = *(const float4*)(xr + kt * 32);
                a1 = *(const float4*)(xr + kt * 32 + 4);
            }
            union { bf16x8 v; unsigned short s[8]; } u;
            u.s[0] = f2bf(a0.x); u.s[1] = f2bf(a0.y);
            u.s[2] = f2bf(a0.z); u.s[3] = f2bf(a0.w);
            u.s[4] = f2bf(a1.x); u.s[5] = f2bf(a1.y);
            u.s[6] = f2bf(a1.z); u.s[7] = f2bf(a1.w);
            af[kt] = u.v;
        }
    }

    // ---- Q = (x Wq^T + b) * scale -> SC (wave-private rows, no barrier) ----
#pragma unroll 4
    for (int ct = 0; ct < 12; ++ct) {
        f32x4 acc = {0.f, 0.f, 0.f, 0.f};
        const unsigned short* wr = wqkv + (size_t)(ct * 16 + l15) * TC + quad * 8;
#pragma unroll
        for (int kt = 0; kt < 6; ++kt)
            acc = __builtin_amdgcn_mfma_f32_16x16x32_bf16(
                af[kt], *(const bf16x8*)(wr + kt * 32), acc, 0, 0, 0);
        const int d = ct * 16 + l15;
        const float bias = qb[d];
#pragma unroll
        for (int r = 0; r < 4; ++r)
            SC[(row0 + r) * SSTR + d] = f2bf((acc[r] + bias) * SCALE);
    }
    // Q fragments for all heads into registers (own rows -> no barrier)
    bf16x8 aq[NH];
#pragma unroll
    for (int h = 0; h < NH; ++h)
        aq[h] = *(const bf16x8*)&SC[arow * SSTR + h * 32 + quad * 8];

    const float* cmbb = cmb + (size_t)((b % nW) * NH) * NN;
    f32x4 oacc0[2], oacc1[2];

    // ---- head loop: FULLY UNROLLED (all array indices compile-time) ----
#pragma unroll
    for (int h = 0; h < NH; ++h) {
        if (h) __syncthreads();   // all waves done reading prev KSh/VTh

        // ---- K_h, V_h: 4 independent MFMA chains, B streamed from L2 ----
#pragma unroll
        for (int cc = 0; cc < 4; ++cc) {
            const int mat = cc >> 1;           // 0 = K, 1 = V
            const int ct  = cc & 1;
            const unsigned short* wr =
                wqkv + (size_t)((1 + mat) * TC + h * 32 + ct * 16 + l15) * TC + quad * 8;
            f32x4 acc = {0.f, 0.f, 0.f, 0.f};
#pragma unroll
            for (int kt = 0; kt < 6; ++kt)
                acc = __builtin_amdgcn_mfma_f32_16x16x32_bf16(
                    af[kt], *(const bf16x8*)(wr + kt * 32), acc, 0, 0, 0);
            const int d = ct * 16 + l15;       // 0..31 within head
            const float bias = qb[(1 + mat) * TC + h * 32 + d];
            if (mat == 0) {
#pragma unroll
                for (int r = 0; r < 4; ++r)
                    KSh[(row0 + r) * KSTR + d] = f2bf(acc[r] + bias);
            } else {
#pragma unroll
                for (int r = 0; r < 4; ++r)
                    VTh[d * VSTR + row0 + r] = f2bf(acc[r] + bias);
            }
        }
        __syncthreads();          // KSh/VTh visible to all waves

        // ---- S = Q K^T : 4 col-tiles, K=32 ----
        f32x4 sacc[4];
#pragma unroll
        for (int tc = 0; tc < 4; ++tc) {
            bf16x8 bk = *(const bf16x8*)&KSh[(tc * 16 + l15) * KSTR + quad * 8];
            f32x4 z = {0.f, 0.f, 0.f, 0.f};
            sacc[tc] = __builtin_amdgcn_mfma_f32_16x16x32_bf16(aq[h], bk, z, 0, 0, 0);
        }
        // ---- bias+mask (direct L2 reads, scheduler hoists) + softmax ----
        const float* cp = cmbb + (size_t)h * NN;
        float sv[4][4];
        float mx[4] = {NEG_INF, NEG_INF, NEG_INF, NEG_INF};
#pragma unroll
        for (int tc = 0; tc < 4; ++tc) {
            int m = tc * 16 + l15;
#pragma unroll
            for (int r = 0; r < 4; ++r) {
                int n = row0 + r;
                float s = NEG_INF;
                if (m < TN) {
                    s = sacc[tc][r];
                    if (n < TN) s += cp[n * TN + m];
                }
                sv[tc][r] = s;
                mx[r] = fmaxf(mx[r], s);
            }
        }
#pragma unroll
        for (int r = 0; r < 4; ++r) {
            mx[r] = fmaxf(mx[r], __shfl_xor(mx[r], 1));
            mx[r] = fmaxf(mx[r], __shfl_xor(mx[r], 2));
            mx[r] = fmaxf(mx[r], __shfl_xor(mx[r], 4));
            mx[r] = fmaxf(mx[r], __shfl_xor(mx[r], 8));
        }
        float sm[4] = {0.f, 0.f, 0.f, 0.f};
#pragma unroll
        for (int tc = 0; tc < 4; ++tc)
#pragma unroll
            for (int r = 0; r < 4; ++r) {
                float p = __expf(sv[tc][r] - mx[r]);
                sv[tc][r] = p;
                sm[r] += p;
            }
#pragma unroll
        for (int r = 0; r < 4; ++r) {
            sm[r] += __shfl_xor(sm[r], 1);
            sm[r] += __shfl_xor(sm[r], 2);
            sm[r] += __shfl_xor(sm[r], 4);
            sm[r] += __shfl_xor(sm[r], 8);
            sm[r] = 1.0f / sm[r];
        }
        // P -> SC cols 0..63 (wave-private rows)
#pragma unroll
        for (int tc = 0; tc < 4; ++tc)
#pragma unroll
            for (int r = 0; r < 4; ++r)
                SC[(row0 + r) * SSTR + tc * 16 + l15] = f2bf(sv[tc][r] * sm[r]);

        // ---- out_h = P V : 2 d-tiles, K=64 ----
#pragma unroll
        for (int dt = 0; dt < 2; ++dt) {
            f32x4 pacc = {0.f, 0.f, 0.f, 0.f};
#pragma unroll
            for (int kt = 0; kt < 2; ++kt) {
                bf16x8 ap = *(const bf16x8*)&SC[arow * SSTR + kt * 32 + quad * 8];
                bf16x8 bv = *(const bf16x8*)&VTh[(dt * 16 + l15) * VSTR + kt * 32 + quad * 8];
                pacc = __builtin_amdgcn_mfma_f32_16x16x32_bf16(ap, bv, pacc, 0, 0, 0);
            }
            if (h == 0)      oacc0[dt] = pacc;
            else if (h == 1) oacc1[dt] = pacc;
            else {
                // Ao_h -> SC cols h*32.. (own rows; no clash with P cols 0..63)
#pragma unroll
                for (int r = 0; r < 4; ++r)
                    SC[(row0 + r) * SSTR + h * 32 + dt * 16 + l15] = f2bf(pacc[r]);
            }
        }
    }

    // ---- Ao heads 0,1 -> SC cols 0..63 (P region dead) ----
#pragma unroll
    for (int dt = 0; dt < 2; ++dt)
#pragma unroll
        for (int r = 0; r < 4; ++r) {
            SC[(row0 + r) * SSTR + dt * 16 + l15]      = f2bf(oacc0[dt][r]);
            SC[(row0 + r) * SSTR + 32 + dt * 16 + l15] = f2bf(oacc1[dt][r]);
        }

    bf16x8 pf[6];
#pragma unroll
    for (int kt = 0; kt < 6; ++kt)
        pf[kt] = *(const bf16x8*)&SC[arow * SSTR + kt * 32 + quad * 8];

    // ---- proj: out = Ao Wp^T + b, Wp streamed from L2 ----
#pragma unroll 4
    for (int ct = 0; ct < 12; ++ct) {
        f32x4 acc = {0.f, 0.f, 0.f, 0.f};
        const unsigned short* wr = wp + (size_t)(ct * 16 + l15) * TC + quad * 8;
#pragma unroll
        for (int kt = 0; kt < 6; ++kt)
            acc = __builtin_amdgcn_mfma_f32_16x16x32_bf16(
                pf[kt], *(const bf16x8*)(wr + kt * 32), acc, 0, 0, 0);
        const int c = ct * 16 + l15;
        const float bias = pb[c];
#pragma unroll
        for (int r = 0; r < 4; ++r) {
            int n = row0 + r;
            if (n < TN)
                out[((size_t)b * TN + n) * TC + c] = acc[r] + bias;
        }
    }
}

extern "C" void kernel_launch(void* const* d_in, const int* in_sizes, int n_in,
                              void* d_out, int out_size, void* d_ws, size_t ws_size,
                              hipStream_t stream) {
    const float* x    = (const float*)d_in[0];
    const float* mask = (const float*)d_in[1];
    const float* bt   = (const float*)d_in[2];
    const float* qw   = (const float*)d_in[3];
    const float* qb   = (const float*)d_in[4];
    const float* pw   = (const float*)d_in[5];
    const float* pb   = (const float*)d_in[6];
    const int*   ridx = (const int*)d_in[7];

    const int B  = in_sizes[0] / (TN * TC);   // 4096 windows
    const int nW = in_sizes[1] / (TN * TN);   // 64

    unsigned short* wqkvb = (unsigned short*)d_ws;            // 576*192 bf16
    unsigned short* wpb   = wqkvb + 576 * 192;                // 192*192 bf16
    float*          cmb   = (float*)(wpb + 192 * 192);        // nW*6*2401 f32 (~3.7 MB)

    const int total = nW * NH * NN;
    const int prep_threads = 576 * 192 + 192 * 192 + total;

    hipLaunchKernelGGL(prep_kernel, dim3((prep_threads + 255) / 256), dim3(256), 0, stream,
                       qw, pw, bt, ridx, mask, wqkvb, wpb, cmb, total);
    hipLaunchKernelGGL(fused_kernel, dim3(B), dim3(256), 0, stream,
                       x, cmb, wqkvb, qb, wpb, pb, (float*)d_out, nW);
}